// Round 1
// baseline (6757.792 us; speedup 1.0000x reference)
//
#include <hip/hip_runtime.h>
#include <hip/hip_bf16.h>

// HypothesisDecoder: N=8192 pts, H=32 hyps, trilinear(vol1[48^3,128], vol0[24^3,128])
// + pts_feat[64] -> conv1d(k3)x3 (HID=256) w/ BN+ReLU -> conv to 1 -> softmax over H.
// Strategy: pre-transpose vols to channel-last (contiguous 512B gathers) and weights
// to [i][t][o] (coalesced per-channel loads); one 256-thread block per point, fully
// fused in LDS, fp32 VALU compute (no fp32 MFMA on CDNA4).

#define NPTS 8192
#define HH   32
#define PAD  36      // row pitch in floats: 144B = 9*16B -> float4-aligned rows
#define EPSF 1e-5f
#define S1   110592  // 48^3
#define S0   13824   // 24^3

// ---------------- pre-pass: volume transpose [b][c][s] -> [b][s][c] ----------------
__global__ void tvol_kernel(const float* __restrict__ in, float* __restrict__ out, int S) {
    __shared__ float t[32][33];
    const int b  = blockIdx.z;
    const int s0 = blockIdx.x * 32, c0 = blockIdx.y * 32;
    const int tx = threadIdx.x & 31, ty = threadIdx.x >> 5;   // 32x8
    const float* ip = in + ((size_t)b * 128 + c0) * S + s0;
#pragma unroll
    for (int j = 0; j < 32; j += 8)
        t[ty + j][tx] = ip[(size_t)(ty + j) * S + tx];
    __syncthreads();
    float* op = out + ((size_t)b * S + s0) * 128 + c0;
#pragma unroll
    for (int j = 0; j < 32; j += 8)
        op[(size_t)(ty + j) * 128 + tx] = t[tx][ty + j];
}

// ---------------- pre-pass: weight transpose (O,I,3) -> [(i*3+t)*O + o] ----------------
__global__ void twgt_kernel(const float* __restrict__ in, float* __restrict__ out, int O, int I) {
    int idx = blockIdx.x * 256 + threadIdx.x;
    if (idx >= O * I * 3) return;
    int o = idx % O;
    int r = idx / O;          // i*3 + t
    int t = r % 3, i = r / 3;
    out[idx] = in[((size_t)o * I + i) * 3 + t];
}

// ---------------- helpers ----------------
__device__ __forceinline__ void setup_corners(float px, float py, float pz, int D,
                                              int* __restrict__ idx, float* __restrict__ wt) {
    float cx = px * (D - 1), cy = py * (D - 1), cz = pz * (D - 1);
    float fx = floorf(cx), fy = floorf(cy), fz = floorf(cz);
    float rx = cx - fx, ry = cy - fy, rz = cz - fz;
    int ix = (int)fx, iy = (int)fy, iz = (int)fz;
#pragma unroll
    for (int k = 0; k < 8; ++k) {
        int dx = k >> 2, dy = (k >> 1) & 1, dz = k & 1;
        int jx = ix + dx, jy = iy + dy, jz = iz + dz;
        bool valid = (jx >= 0) && (jx < D) && (jy >= 0) && (jy < D) && (jz >= 0) && (jz < D);
        int cxi = min(max(jx, 0), D - 1), cyi = min(max(jy, 0), D - 1), czi = min(max(jz, 0), D - 1);
        float w = (dx ? rx : 1.f - rx) * (dy ? ry : 1.f - ry) * (dz ? rz : 1.f - rz);
        idx[k] = (cxi * D + cyi) * D + czi;
        wt[k]  = valid ? w : 0.f;
    }
}

// acc[h] += wA*f[h-1] + wB*f[h] + wC*f[h+1]  (zero-padded), f = 32-float LDS row
__device__ __forceinline__ void conv_row(const float* __restrict__ f,
                                         float wA, float wB, float wC,
                                         float* __restrict__ acc) {
    float fr[34];
    fr[0] = 0.f; fr[33] = 0.f;
#pragma unroll
    for (int j = 0; j < 8; ++j) {
        const float4 v = *reinterpret_cast<const float4*>(f + 4 * j);
        fr[1 + 4 * j] = v.x; fr[2 + 4 * j] = v.y; fr[3 + 4 * j] = v.z; fr[4 + 4 * j] = v.w;
    }
#pragma unroll
    for (int h = 0; h < 32; ++h)
        acc[h] += wA * fr[h] + wB * fr[h + 1] + wC * fr[h + 2];
}

// ---------------- fused per-point kernel ----------------
__global__ __launch_bounds__(256, 2) void fused_kernel(
    const float* __restrict__ pts, const float* __restrict__ pts_feat,
    const int* __restrict__ pts_batch,
    const float* __restrict__ v0p, long v0s, long v0c,
    const float* __restrict__ v1p, long v1s, long v1c,
    const float* __restrict__ w0p, long w0iS, long w0tS, long w0oS,
    const float* __restrict__ w1p, long w1iS, long w1tS, long w1oS,
    const float* __restrict__ w2p, long w2iS, long w2tS, long w2oS,
    const float* __restrict__ w3p, const float* __restrict__ b3p,
    const float* __restrict__ g0, const float* __restrict__ be0,
    const float* __restrict__ m0, const float* __restrict__ va0,
    const float* __restrict__ g1, const float* __restrict__ be1,
    const float* __restrict__ m1, const float* __restrict__ va1,
    const float* __restrict__ g2, const float* __restrict__ be2,
    const float* __restrict__ m2, const float* __restrict__ va2,
    float* __restrict__ outp) {

    const int n = blockIdx.x;
    const int tid = threadIdx.x;
    const int lane = tid & 63, wv = tid >> 6;

    // A: feat rows 0..255 (f1:0..127, f0:128..255); later x2.   36864B
    // B: rows 0..63 staged pts_feat, then x1, then x3.          36864B
    __shared__ float A[256 * PAD];
    __shared__ float Bb[256 * PAD];
    __shared__ int   idx1s[32][8]; __shared__ float wt1s[32][8];
    __shared__ int   idx0s[32][8]; __shared__ float wt0s[32][8];
    __shared__ float red[128];

    if (tid < 32) {
        const float* pp = pts + ((size_t)n * HH + tid) * 3;
        float px = pp[0], py = pp[1], pz = pp[2];
        setup_corners(px, py, pz, 48, idx1s[tid], wt1s[tid]);
        setup_corners(px, py, pz, 24, idx0s[tid], wt0s[tid]);
    }
    __syncthreads();

    const int b = pts_batch[n];
    {
        const float* v1b = v1p + (size_t)b * (128ull * S1);
        const float* v0b = v0p + (size_t)b * (128ull * S0);
        const size_t c1a = (size_t)lane * v1c, c1b = (size_t)(lane + 64) * v1c;
        const size_t c0a = (size_t)lane * v0c, c0b = (size_t)(lane + 64) * v0c;
        const float* pf = pts_feat + (size_t)n * HH * 64;
        for (int hp = 0; hp < 8; ++hp) {
            int h = wv * 8 + hp;
            float a0 = 0.f, a1 = 0.f, d0 = 0.f, d1 = 0.f;
#pragma unroll
            for (int k = 0; k < 8; ++k) {
                float wk = wt1s[h][k];
                const float* p = v1b + (size_t)idx1s[h][k] * v1s;
                a0 += wk * p[c1a]; a1 += wk * p[c1b];
            }
#pragma unroll
            for (int k = 0; k < 8; ++k) {
                float wk = wt0s[h][k];
                const float* p = v0b + (size_t)idx0s[h][k] * v0s;
                d0 += wk * p[c0a]; d1 += wk * p[c0b];
            }
            A[(lane)*PAD + h]       = a0;   // f1 -> rows 0..127
            A[(lane + 64) * PAD + h]  = a1;
            A[(lane + 128) * PAD + h] = d0; // f0 -> rows 128..255
            A[(lane + 192) * PAD + h] = d1;
            Bb[lane * PAD + h] = pf[(size_t)h * 64 + lane]; // pts_feat -> B rows 0..63
        }
    }
    __syncthreads();

    const int o = tid;
    float acc[32];

    // ---- conv0 (K=320) + BN + ReLU -> Bb ----
    {
#pragma unroll
        for (int h = 0; h < 32; ++h) acc[h] = 0.f;
        const float* wb = w0p + (size_t)o * w0oS;
        for (int i = 0; i < 256; ++i) {
            const float* wp = wb + (size_t)i * w0iS;
            conv_row(&A[i * PAD], wp[0], wp[w0tS], wp[2 * w0tS], acc);
        }
        for (int i = 0; i < 64; ++i) {
            const float* wp = wb + (size_t)(256 + i) * w0iS;
            conv_row(&Bb[i * PAD], wp[0], wp[w0tS], wp[2 * w0tS], acc);
        }
        float s    = g0[o] * rsqrtf(va0[o] + EPSF);
        float bias = be0[o] - m0[o] * s;
        __syncthreads();   // all reads of A & staged pts_feat done
#pragma unroll
        for (int h = 0; h < 32; ++h) acc[h] = fmaxf(fmaf(acc[h], s, bias), 0.f);
#pragma unroll
        for (int j = 0; j < 8; ++j) {
            float4 v = make_float4(acc[4 * j], acc[4 * j + 1], acc[4 * j + 2], acc[4 * j + 3]);
            *reinterpret_cast<float4*>(&Bb[o * PAD + 4 * j]) = v;
        }
        __syncthreads();
    }

    // ---- conv1 (K=256) + BN + ReLU: Bb -> A ----
    {
#pragma unroll
        for (int h = 0; h < 32; ++h) acc[h] = 0.f;
        const float* wb = w1p + (size_t)o * w1oS;
        for (int i = 0; i < 256; ++i) {
            const float* wp = wb + (size_t)i * w1iS;
            conv_row(&Bb[i * PAD], wp[0], wp[w1tS], wp[2 * w1tS], acc);
        }
        float s    = g1[o] * rsqrtf(va1[o] + EPSF);
        float bias = be1[o] - m1[o] * s;
#pragma unroll
        for (int h = 0; h < 32; ++h) acc[h] = fmaxf(fmaf(acc[h], s, bias), 0.f);
#pragma unroll
        for (int j = 0; j < 8; ++j) {   // A (feat) is dead: safe to overwrite
            float4 v = make_float4(acc[4 * j], acc[4 * j + 1], acc[4 * j + 2], acc[4 * j + 3]);
            *reinterpret_cast<float4*>(&A[o * PAD + 4 * j]) = v;
        }
        __syncthreads();
    }

    // ---- conv2 (K=256) + BN + ReLU: A -> Bb ----
    {
#pragma unroll
        for (int h = 0; h < 32; ++h) acc[h] = 0.f;
        const float* wb = w2p + (size_t)o * w2oS;
        for (int i = 0; i < 256; ++i) {
            const float* wp = wb + (size_t)i * w2iS;
            conv_row(&A[i * PAD], wp[0], wp[w2tS], wp[2 * w2tS], acc);
        }
        float s    = g2[o] * rsqrtf(va2[o] + EPSF);
        float bias = be2[o] - m2[o] * s;
#pragma unroll
        for (int h = 0; h < 32; ++h) acc[h] = fmaxf(fmaf(acc[h], s, bias), 0.f);
#pragma unroll
        for (int j = 0; j < 8; ++j) {   // Bb (x1) dead after conv1's compute barrier
            float4 v = make_float4(acc[4 * j], acc[4 * j + 1], acc[4 * j + 2], acc[4 * j + 3]);
            *reinterpret_cast<float4*>(&Bb[o * PAD + 4 * j]) = v;
        }
        __syncthreads();
    }

    // ---- conv3 (256 -> 1) + softmax over H ----
    {
#pragma unroll
        for (int h = 0; h < 32; ++h) acc[h] = 0.f;
        float wA = w3p[o * 3 + 0], wB = w3p[o * 3 + 1], wC = w3p[o * 3 + 2];
        conv_row(&Bb[o * PAD], wA, wB, wC, acc);
        // 64-lane butterfly: every lane ends with the wave's channel-sum per h
#pragma unroll
        for (int m2 = 1; m2 < 64; m2 <<= 1)
#pragma unroll
            for (int h = 0; h < 32; ++h)
                acc[h] += __shfl_xor(acc[h], m2, 64);
        if (lane == 0) {
#pragma unroll
            for (int h = 0; h < 32; ++h) red[wv * 32 + h] = acc[h];
        }
        __syncthreads();
        if (tid < 32) {
            float l = red[tid] + red[32 + tid] + red[64 + tid] + red[96 + tid] + b3p[0];
            float mx = l;
#pragma unroll
            for (int m2 = 1; m2 < 32; m2 <<= 1) mx = fmaxf(mx, __shfl_xor(mx, m2, 64));
            float e = expf(l - mx);
            float ssum = e;
#pragma unroll
            for (int m2 = 1; m2 < 32; m2 <<= 1) ssum += __shfl_xor(ssum, m2, 64);
            outp[(size_t)n * HH + tid] = e / ssum;
        }
    }
}

extern "C" void kernel_launch(void* const* d_in, const int* in_sizes, int n_in,
                              void* d_out, int out_size, void* d_ws, size_t ws_size,
                              hipStream_t stream) {
    const float* pts      = (const float*)d_in[0];
    const float* pts_feat = (const float*)d_in[1];
    const int*   pbatch   = (const int*)d_in[2];
    const float* vol0     = (const float*)d_in[3];
    const float* vol1     = (const float*)d_in[4];
    const float* w0 = (const float*)d_in[5];
    const float* w1 = (const float*)d_in[6];
    const float* w2 = (const float*)d_in[7];
    const float* w3 = (const float*)d_in[8];
    const float* b3 = (const float*)d_in[9];
    const float* g0 = (const float*)d_in[10];
    const float* be0 = (const float*)d_in[11];
    const float* m0 = (const float*)d_in[12];
    const float* va0 = (const float*)d_in[13];
    const float* g1 = (const float*)d_in[14];
    const float* be1 = (const float*)d_in[15];
    const float* m1 = (const float*)d_in[16];
    const float* va1 = (const float*)d_in[17];
    const float* g2 = (const float*)d_in[18];
    const float* be2 = (const float*)d_in[19];
    const float* m2 = (const float*)d_in[20];
    const float* va2 = (const float*)d_in[21];
    float* outp = (float*)d_out;

    const size_t v1f = 4ull * 128 * S1;   // 56,623,104 floats
    const size_t v0f = 4ull * 128 * S0;   //  7,077,888 floats
    const size_t w0f = 256ull * 320 * 3, w1f = 256ull * 256 * 3, w2f = w1f;
    const size_t volsBytes = (v1f + v0f) * 4;
    const size_t wBytes    = (w0f + w1f + w2f) * 4;

    float* wsf = (float*)d_ws;
    const bool tw = ws_size >= wBytes;
    const bool tv = ws_size >= wBytes + volsBytes;

    const float *v1p = vol1, *v0p = vol0;
    long v1s = 1, v1c = S1, v0s = 1, v0c = S0;          // direct: cell stride 1, chan stride S
    const float *w0p = w0, *w1p = w1, *w2p = w2;
    long w0iS = 3, w0tS = 1, w0oS = 320 * 3;
    long w1iS = 3, w1tS = 1, w1oS = 256 * 3;
    long w2iS = 3, w2tS = 1, w2oS = 256 * 3;

    size_t off = 0;
    if (tv) {
        float* v1t = wsf;
        float* v0t = wsf + v1f;
        off = v1f + v0f;
        tvol_kernel<<<dim3(S1 / 32, 4, 4), 256, 0, stream>>>(vol1, v1t, S1);
        tvol_kernel<<<dim3(S0 / 32, 4, 4), 256, 0, stream>>>(vol0, v0t, S0);
        v1p = v1t; v1s = 128; v1c = 1;                  // transposed: channel-last
        v0p = v0t; v0s = 128; v0c = 1;
    }
    if (tw) {
        float* a = wsf + off;
        twgt_kernel<<<(int)((w0f + 255) / 256), 256, 0, stream>>>(w0, a, 256, 320);
        w0p = a; w0iS = 768; w0tS = 256; w0oS = 1; a += w0f;
        twgt_kernel<<<(int)((w1f + 255) / 256), 256, 0, stream>>>(w1, a, 256, 256);
        w1p = a; w1iS = 768; w1tS = 256; w1oS = 1; a += w1f;
        twgt_kernel<<<(int)((w2f + 255) / 256), 256, 0, stream>>>(w2, a, 256, 256);
        w2p = a; w2iS = 768; w2tS = 256; w2oS = 1;
    }

    fused_kernel<<<NPTS, 256, 0, stream>>>(pts, pts_feat, pbatch,
        v0p, v0s, v0c, v1p, v1s, v1c,
        w0p, w0iS, w0tS, w0oS, w1p, w1iS, w1tS, w1oS, w2p, w2iS, w2tS, w2oS,
        w3, b3, g0, be0, m0, va0, g1, be1, m1, va1, g2, be2, m2, va2, outp);
}

// Round 3
// 1002.385 us; speedup vs baseline: 6.7417x; 6.7417x over previous
//
#include <hip/hip_runtime.h>

// HypothesisDecoder on MFMA (fp16 single-pass, fp32 accum).
// Pipeline per 512-thr block (G=4 points):
//   gather (fp16 channel-last vols, L3-resident) -> F[pt][34][324] fp16 in LDS
//   conv0/1/2 as tap-major GEMM on v_mfma_f32_32x32x16_f16:
//     M=128 (4 pts x 32 hyp), N=256 (8 waves x 32 cols), K=3*Cin
//     A from LDS (2xb64, 2-way-free banks), B from global frag-packed (1xb128/lane, L2-hot)
//   BN+ReLU -> fp16 back to F; conv3 + softmax on VALU.

typedef _Float16 half8 __attribute__((ext_vector_type(8)));
typedef float floatx16 __attribute__((ext_vector_type(16)));

#define NPTS  8192
#define HH    32
#define GPTS  4
#define PITCH 324        // halves per F row; 648B stride = 162 banks == 2 mod 32
#define S1    110592     // 48^3
#define S0    13824      // 24^3
#define EPSF  1e-5f

// ---------- prep: vol [B][128][S] fp32 -> [B][S][128] fp16 ----------
__global__ void tvol_h(const float* __restrict__ in, ushort* __restrict__ out, int S) {
    __shared__ float t[32][33];
    const int b  = blockIdx.z;
    const int s0 = blockIdx.x * 32, c0 = blockIdx.y * 32;
    const int tx = threadIdx.x & 31, ty = threadIdx.x >> 5;   // 32x8
    const float* ip = in + ((size_t)b * 128 + c0) * S + s0;
#pragma unroll
    for (int j = 0; j < 32; j += 8)
        t[ty + j][tx] = ip[(size_t)(ty + j) * S + tx];
    __syncthreads();
    ushort* op = out + ((size_t)b * S + s0) * 128 + c0;
#pragma unroll
    for (int j = 0; j < 32; j += 8)
        op[(size_t)(ty + j) * 128 + tx] = __builtin_bit_cast(ushort, (_Float16)t[tx][ty + j]);
}

// ---------- prep: weights (O=256,I,3) -> MFMA B-fragment order ----------
// dst[(((kc*8 + nt)*64 + lane)*8 + j)] = fp16( w[o][i][t] )
//   o = nt*32 + (lane&31); t = kc/(I/16); i = (kc%(I/16))*16 + (lane>>5)*8 + j
__global__ void wprep(const float* __restrict__ w, ushort* __restrict__ dst, int I, int KC) {
    int tid = blockIdx.x * 256 + threadIdx.x;
    if (tid >= KC * 4096) return;
    int j    = tid & 7;
    int lane = (tid >> 3) & 63;
    int nt   = (tid >> 9) & 7;
    int kc   = tid >> 12;
    int I16  = I / 16;
    int o    = nt * 32 + (lane & 31);
    int t    = kc / I16;
    int iw   = (kc % I16) * 16 + (lane >> 5) * 8 + j;
    float v  = w[((size_t)o * I + iw) * 3 + t];
    dst[tid] = __builtin_bit_cast(ushort, (_Float16)v);
}

// ---------- helpers ----------
__device__ __forceinline__ void setup_corners(float px, float py, float pz, int D,
                                              int* __restrict__ idx, float* __restrict__ wt) {
    float cx = px * (D - 1), cy = py * (D - 1), cz = pz * (D - 1);
    float fx = floorf(cx), fy = floorf(cy), fz = floorf(cz);
    float rx = cx - fx, ry = cy - fy, rz = cz - fz;
    int ix = (int)fx, iy = (int)fy, iz = (int)fz;
#pragma unroll
    for (int k = 0; k < 8; ++k) {
        int dx = k >> 2, dy = (k >> 1) & 1, dz = k & 1;
        int jx = ix + dx, jy = iy + dy, jz = iz + dz;
        bool valid = (jx >= 0) && (jx < D) && (jy >= 0) && (jy < D) && (jz >= 0) && (jz < D);
        int cxi = min(max(jx, 0), D - 1), cyi = min(max(jy, 0), D - 1), czi = min(max(jz, 0), D - 1);
        float w = (dx ? rx : 1.f - rx) * (dy ? ry : 1.f - ry) * (dz ? rz : 1.f - rz);
        idx[k] = (cxi * D + cyi) * D + czi;
        wt[k]  = valid ? w : 0.f;
    }
}

__device__ __forceinline__ uint packh2(float a, float b) {
    ushort ua = __builtin_bit_cast(ushort, (_Float16)a);
    ushort ub = __builtin_bit_cast(ushort, (_Float16)b);
    return (uint)ua | ((uint)ub << 16);
}

__device__ __forceinline__ half8 lda(const ushort* p) {   // 16B LDS read, 8B-aligned
    uint2 lo = *(const uint2*)p;
    uint2 hi = *(const uint2*)(p + 4);
    uint4 u; u.x = lo.x; u.y = lo.y; u.z = hi.x; u.w = hi.y;
    return __builtin_bit_cast(half8, u);
}

// ---------- conv layer: GEMM M=128, N=256 (8 waves x 32), K=3*16*I16 ----------
template <int I16>
__device__ __forceinline__ void conv_layer(
    ushort (&F)[GPTS][34][PITCH], const ushort* __restrict__ wf,
    const float* __restrict__ gg, const float* __restrict__ bb,
    const float* __restrict__ mm, const float* __restrict__ vv,
    int wv, int lane)
{
    constexpr int KC = 3 * I16;
    const int ch = wv * 32 + (lane & 31);
    const float sc = gg[ch] / sqrtf(vv[ch] + EPSF);
    const float bs = bb[ch] - mm[ch] * sc;

    floatx16 acc[GPTS];
#pragma unroll
    for (int p = 0; p < GPTS; ++p)
#pragma unroll
        for (int r = 0; r < 16; ++r) acc[p][r] = 0.f;

    const ushort* aB = &F[0][0][0] + (lane & 31) * PITCH + (lane >> 5) * 8;
    const ushort* bB = wf + (size_t)wv * 512 + (size_t)lane * 8;

    half8 p0 = *(const half8*)(bB);
    half8 p1 = *(const half8*)(bB + 1 * 4096);
    half8 p2 = *(const half8*)(bB + 2 * 4096);
    half8 p3 = *(const half8*)(bB + 3 * 4096);

    int t = 0, ic = 0;
#define STEP(BREG, KNEXT)                                                        \
    {                                                                            \
        const ushort* ap = aB + t * PITCH + ic * 16;                             \
        half8 a0 = lda(ap);                                                      \
        half8 a1 = lda(ap + 1 * 34 * PITCH);                                     \
        half8 a2 = lda(ap + 2 * 34 * PITCH);                                     \
        half8 a3 = lda(ap + 3 * 34 * PITCH);                                     \
        acc[0] = __builtin_amdgcn_mfma_f32_32x32x16_f16(a0, BREG, acc[0], 0, 0, 0); \
        acc[1] = __builtin_amdgcn_mfma_f32_32x32x16_f16(a1, BREG, acc[1], 0, 0, 0); \
        acc[2] = __builtin_amdgcn_mfma_f32_32x32x16_f16(a2, BREG, acc[2], 0, 0, 0); \
        acc[3] = __builtin_amdgcn_mfma_f32_32x32x16_f16(a3, BREG, acc[3], 0, 0, 0); \
        BREG = *(const half8*)(bB + (size_t)min(KNEXT, KC - 1) * 4096);          \
        if (++ic == I16) { ic = 0; ++t; }                                        \
    }

#pragma unroll 1
    for (int kc = 0; kc < KC; kc += 4) {
        STEP(p0, kc + 4)
        STEP(p1, kc + 5)
        STEP(p2, kc + 6)
        STEP(p3, kc + 7)
    }
#undef STEP

    __syncthreads();   // all waves done READING F
#pragma unroll
    for (int p = 0; p < GPTS; ++p)
#pragma unroll
        for (int r = 0; r < 16; ++r) {
            int h = (r & 3) + 8 * (r >> 2) + 4 * (lane >> 5);
            float v = fmaxf(fmaf(acc[p][r], sc, bs), 0.f);
            F[p][h + 1][ch] = __builtin_bit_cast(ushort, (_Float16)v);
        }
    __syncthreads();
}

// ---------- fused kernel ----------
__global__ __launch_bounds__(512, 2) void fused_kernel(
    const float* __restrict__ pts, const float* __restrict__ pf,
    const int* __restrict__ pbatch,
    const ushort* __restrict__ v1t, const ushort* __restrict__ v0t,
    const ushort* __restrict__ wf0, const ushort* __restrict__ wf1,
    const ushort* __restrict__ wf2,
    const float* __restrict__ w3, const float* __restrict__ b3,
    const float* __restrict__ g0, const float* __restrict__ be0,
    const float* __restrict__ m0, const float* __restrict__ va0,
    const float* __restrict__ g1, const float* __restrict__ be1,
    const float* __restrict__ m1, const float* __restrict__ va1,
    const float* __restrict__ g2, const float* __restrict__ be2,
    const float* __restrict__ m2, const float* __restrict__ va2,
    float* __restrict__ outp)
{
    __shared__ ushort F[GPTS][34][PITCH];     // 88128 B
    __shared__ float  w3s[768];

    const int tid = threadIdx.x, lane = tid & 63, wv = tid >> 6;

    if (tid < 256) {
        w3s[tid]       = w3[tid];
        w3s[256 + tid] = w3[256 + tid];
        w3s[512 + tid] = w3[512 + tid];
    }

    // zero pad rows 0 and 33
    for (int i = tid; i < 162 * GPTS; i += 512) {
        int p = i / 162, c = i - p * 162;
        ((uint*)&F[p][0][0])[c]  = 0u;
        ((uint*)&F[p][33][0])[c] = 0u;
    }

    // ---- gather: 128 (pt,h) groups x 4 ch-slice threads ----
    {
        const int g = tid >> 2, cj = tid & 3;
        const int pt = g >> 5, h = g & 31;
        const int n = blockIdx.x * GPTS + pt;
        const float* pp = pts + ((size_t)n * HH + h) * 3;
        const float px = pp[0], py = pp[1], pz = pp[2];
        const int bi = pbatch[n];
        int idx1[8]; float wt1[8]; setup_corners(px, py, pz, 48, idx1, wt1);
        int idx0[8]; float wt0[8]; setup_corners(px, py, pz, 24, idx0, wt0);

        // vol1 -> channels 0..127
        {
            const ushort* vb = v1t + (size_t)bi * (128ull * S1) + cj * 32;
            float acc[32];
#pragma unroll
            for (int k = 0; k < 32; ++k) acc[k] = 0.f;
#pragma unroll
            for (int c = 0; c < 8; ++c) {
                const half8* p = (const half8*)(vb + (size_t)idx1[c] * 128);
                float w = wt1[c];
#pragma unroll
                for (int q = 0; q < 4; ++q) {
                    half8 x = p[q];
#pragma unroll
                    for (int e = 0; e < 8; ++e) acc[q * 8 + e] += w * (float)x[e];
                }
            }
            ushort* fr = &F[pt][h + 1][cj * 32];
#pragma unroll
            for (int k = 0; k < 8; ++k) {
                uint2 u; u.x = packh2(acc[4 * k], acc[4 * k + 1]);
                u.y = packh2(acc[4 * k + 2], acc[4 * k + 3]);
                ((uint2*)fr)[k] = u;
            }
        }
        // vol0 -> channels 128..255
        {
            const ushort* vb = v0t + (size_t)bi * (128ull * S0) + cj * 32;
            float acc[32];
#pragma unroll
            for (int k = 0; k < 32; ++k) acc[k] = 0.f;
#pragma unroll
            for (int c = 0; c < 8; ++c) {
                const half8* p = (const half8*)(vb + (size_t)idx0[c] * 128);
                float w = wt0[c];
#pragma unroll
                for (int q = 0; q < 4; ++q) {
                    half8 x = p[q];
#pragma unroll
                    for (int e = 0; e < 8; ++e) acc[q * 8 + e] += w * (float)x[e];
                }
            }
            ushort* fr = &F[pt][h + 1][128 + cj * 32];
#pragma unroll
            for (int k = 0; k < 8; ++k) {
                uint2 u; u.x = packh2(acc[4 * k], acc[4 * k + 1]);
                u.y = packh2(acc[4 * k + 2], acc[4 * k + 3]);
                ((uint2*)fr)[k] = u;
            }
        }
        // pts_feat -> channels 256..319
        {
            const float* pfp = pf + ((size_t)n * HH + h) * 64 + cj * 16;
            ushort* fr = &F[pt][h + 1][256 + cj * 16];
#pragma unroll
            for (int k = 0; k < 4; ++k) {
                float4 v = *(const float4*)(pfp + 4 * k);
                uint2 u; u.x = packh2(v.x, v.y); u.y = packh2(v.z, v.w);
                ((uint2*)fr)[k] = u;
            }
        }
    }
    __syncthreads();

    // ---- conv layers on MFMA ----
    conv_layer<20>(F, wf0, g0, be0, m0, va0, wv, lane);
    conv_layer<16>(F, wf1, g1, be1, m1, va1, wv, lane);
    conv_layer<16>(F, wf2, g2, be2, m2, va2, wv, lane);

    // ---- conv3 (256->1) + softmax over 32 hyps ----
    if (wv < GPTS) {
        const int hh = lane & 31, ihalf = lane >> 5;
        float a = 0.f;
#pragma unroll
        for (int t = 0; t < 3; ++t) {
            const ushort* fr = &F[wv][hh + t][ihalf * 128];
#pragma unroll
            for (int b8 = 0; b8 < 16; ++b8) {
                half8 x = lda(fr + b8 * 8);
                int i0 = ihalf * 128 + b8 * 8;
#pragma unroll
                for (int j = 0; j < 8; ++j)
                    a += (float)x[j] * w3s[(i0 + j) * 3 + t];
            }
        }
        a += __shfl_xor(a, 32, 64);
        a += b3[0];
        float mx = a;
#pragma unroll
        for (int m = 16; m >= 1; m >>= 1) mx = fmaxf(mx, __shfl_xor(mx, m, 64));
        float e = expf(a - mx);
        float s = e;
#pragma unroll
        for (int m = 16; m >= 1; m >>= 1) s += __shfl_xor(s, m, 64);
        if (lane < 32)
            outp[((size_t)(blockIdx.x * GPTS + wv)) * HH + hh] = e / s;
    }
}

extern "C" void kernel_launch(void* const* d_in, const int* in_sizes, int n_in,
                              void* d_out, int out_size, void* d_ws, size_t ws_size,
                              hipStream_t stream) {
    const float* pts      = (const float*)d_in[0];
    const float* pts_feat = (const float*)d_in[1];
    const int*   pbatch   = (const int*)d_in[2];
    const float* vol0     = (const float*)d_in[3];
    const float* vol1     = (const float*)d_in[4];
    const float* w0 = (const float*)d_in[5];
    const float* w1 = (const float*)d_in[6];
    const float* w2 = (const float*)d_in[7];
    const float* w3 = (const float*)d_in[8];
    const float* b3 = (const float*)d_in[9];
    const float* g0 = (const float*)d_in[10];
    const float* be0 = (const float*)d_in[11];
    const float* m0 = (const float*)d_in[12];
    const float* va0 = (const float*)d_in[13];
    const float* g1 = (const float*)d_in[14];
    const float* be1 = (const float*)d_in[15];
    const float* m1 = (const float*)d_in[16];
    const float* va1 = (const float*)d_in[17];
    const float* g2 = (const float*)d_in[18];
    const float* be2 = (const float*)d_in[19];
    const float* m2 = (const float*)d_in[20];
    const float* va2 = (const float*)d_in[21];
    float* outp = (float*)d_out;

    // ws layout (ushort units)
    const size_t o_v1 = 0;
    const size_t s_v1 = 4ull * S1 * 128;          // 56,623,104
    const size_t o_v0 = o_v1 + s_v1;
    const size_t s_v0 = 4ull * S0 * 128;          //  7,077,888
    const size_t o_w0 = o_v0 + s_v0;
    const size_t s_w0 = 60ull * 4096;             // 245,760
    const size_t o_w1 = o_w0 + s_w0;
    const size_t s_w1 = 48ull * 4096;
    const size_t o_w2 = o_w1 + s_w1;
    const size_t s_w2 = 48ull * 4096;
    const size_t need = (o_w2 + s_w2) * 2 + 65536;
    if (ws_size < need) return;   // cannot run without scratch

    ushort* wsu = (ushort*)d_ws;
    ushort* v1t = wsu + o_v1;
    ushort* v0t = wsu + o_v0;
    ushort* wf0 = wsu + o_w0;
    ushort* wf1 = wsu + o_w1;
    ushort* wf2 = wsu + o_w2;

    tvol_h<<<dim3(S1 / 32, 4, 4), 256, 0, stream>>>(vol1, v1t, S1);
    tvol_h<<<dim3(S0 / 32, 4, 4), 256, 0, stream>>>(vol0, v0t, S0);
    wprep<<<(int)((60 * 4096 + 255) / 256), 256, 0, stream>>>(w0, wf0, 320, 60);
    wprep<<<(int)((48 * 4096 + 255) / 256), 256, 0, stream>>>(w1, wf1, 256, 48);
    wprep<<<(int)((48 * 4096 + 255) / 256), 256, 0, stream>>>(w2, wf2, 256, 48);

    fused_kernel<<<NPTS / GPTS, 512, 0, stream>>>(
        pts, pts_feat, pbatch, v1t, v0t, wf0, wf1, wf2, w3, b3,
        g0, be0, m0, va0, g1, be1, m1, va1, g2, be2, m2, va2, outp);
}